// Round 3
// baseline (277.814 us; speedup 1.0000x reference)
//
#include <hip/hip_runtime.h>
#include <hip/hip_bf16.h>

typedef __attribute__((ext_vector_type(4))) float f32x4;

__device__ __forceinline__ void async_copy16(void* lds, const void* g) {
  __builtin_amdgcn_global_load_lds(
      (const __attribute__((address_space(1))) unsigned int*)g,
      (__attribute__((address_space(3))) unsigned int*)lds,
      16, 0, 0);
}

// Two rows per wave: fp32 -> fp8 e4m3 convert (packed cvt) + fp32 row norms.
__global__ __launch_bounds__(256)
void rbf_prep(const float* __restrict__ x, const float* __restrict__ y,
              unsigned char* __restrict__ xb, unsigned char* __restrict__ yb,
              float* __restrict__ xsq, float* __restrict__ ysq,
              int n, int m) {
  const int gw   = (int)((blockIdx.x * blockDim.x + threadIdx.x) >> 6);
  const int lane = threadIdx.x & 63;
  const int half = lane >> 5;   // which of the wave's 2 rows
  const int l32  = lane & 31;   // 32 lanes x float4 = 128 floats = 1 row
  const int rid  = gw * 2 + half;
  if (rid >= n + m) return;
  const float* src;
  unsigned char* dst;
  float* nrm;
  int row;
  if (rid < n) { src = x; dst = xb; nrm = xsq; row = rid; }
  else         { src = y; dst = yb; nrm = ysq; row = rid - n; }
  const float4 v = ((const float4*)(src + (size_t)row * 128))[l32];
  float ss = v.x * v.x + v.y * v.y + v.z * v.z + v.w * v.w;
  #pragma unroll
  for (int off = 16; off > 0; off >>= 1) ss += __shfl_down(ss, off, 64);
  int packed = 0;
  packed = __builtin_amdgcn_cvt_pk_fp8_f32(v.x, v.y, packed, false); // bytes 0,1
  packed = __builtin_amdgcn_cvt_pk_fp8_f32(v.z, v.w, packed, true);  // bytes 2,3
  ((int*)(dst + (size_t)row * 128))[l32] = packed;
  if (l32 == 0) nrm[row] = ss;
}

// 128x128 output tile per block; 4 waves in 2x2, each wave 64x64 via 4x4
// mfma_f32_16x16x32_fp8_fp8. Full K=128 staged once (2 x 16KB LDS ->
// 3 blocks/CU with launch_bounds(256,3); VGPR cap 170, no spills).
// LDS layout: [row][16B slot], slot = chunk ^ (row & 7) (XOR swizzle applied
// on the global SOURCE address, since global_load_lds dest is uniform+lane*16).
__global__ __launch_bounds__(256, 3)
void rbf_gemm(const unsigned char* __restrict__ xb, const unsigned char* __restrict__ yb,
              const float* __restrict__ xsq, const float* __restrict__ ysq,
              const float* __restrict__ gptr, float* __restrict__ out,
              int mcols) {
  __shared__ __align__(16) unsigned char xs[128 * 128];
  __shared__ __align__(16) unsigned char ys[128 * 128];
  const int tid  = threadIdx.x;
  const int lane = tid & 63;
  const int wv   = tid >> 6;
  const int bn = blockIdx.x, bm = blockIdx.y;
  const int wm = wv >> 1, wn = wv & 1;
  const int quad = lane >> 4, l15 = lane & 15;

  // ---- stage both tiles (rows are contiguous 128B in global; coalesced) ----
  {
    const int r0   = lane >> 3;          // 0..7: row within an 8-row segment
    const int slot = lane & 7;           // 16B slot within the 128B row
    const int c    = slot ^ r0;          // source 16B chunk (r0 == row&7)
    const size_t xrow0 = (size_t)bm * 128;
    const size_t yrow0 = (size_t)bn * 128;
    #pragma unroll
    for (int ii = 0; ii < 4; ++ii) {
      const int seg = wv + ii * 4;       // 16 segments of 1KB (8 rows) per tile
      const int r = seg * 8 + r0;
      async_copy16(xs + seg * 1024, xb + (xrow0 + r) * 128 + c * 16);
      async_copy16(ys + seg * 1024, yb + (yrow0 + r) * 128 + c * 16);
    }
  }

  f32x4 acc[4][4];
  #pragma unroll
  for (int i = 0; i < 4; ++i)
    #pragma unroll
    for (int j = 0; j < 4; ++j)
      acc[i][j] = (f32x4){0.f, 0.f, 0.f, 0.f};

  __syncthreads();  // compiler emits vmcnt(0) drain before s_barrier

  // ---- K loop: 4 steps of K=32 ----
  const int sub = (quad & 1) * 8;        // byte offset within the 16B slot
  #pragma unroll
  for (int kk = 0; kk < 4; ++kk) {
    const int c16 = kk * 2 + (quad >> 1);   // 16B chunk along K for this quad
    long af[4], bf[4];
    #pragma unroll
    for (int t = 0; t < 4; ++t) {
      const int ra = wm * 64 + t * 16 + l15;
      const int rb = wn * 64 + t * 16 + l15;
      af[t] = *(const long*)(xs + ra * 128 + (c16 ^ (ra & 7)) * 16 + sub);
      bf[t] = *(const long*)(ys + rb * 128 + (c16 ^ (rb & 7)) * 16 + sub);
    }
    #pragma unroll
    for (int i = 0; i < 4; ++i)
      #pragma unroll
      for (int j = 0; j < 4; ++j)
        acc[i][j] = __builtin_amdgcn_mfma_f32_16x16x32_fp8_fp8(af[i], bf[j], acc[i][j], 0, 0, 0);
  }

  // ---- epilogue: sq = xsq + ysq - 2*dot, clamp, exp ----
  const float ng2 = -gptr[0] * 1.4426950408889634f;  // -gamma * log2(e)
  float ysqc[4];
  const int col0 = bn * 128 + wn * 64 + l15;
  #pragma unroll
  for (int j = 0; j < 4; ++j) ysqc[j] = ysq[col0 + j * 16];
  const int row0 = bm * 128 + wm * 64 + quad * 4;  // D row = quad*4 + reg
  #pragma unroll
  for (int i = 0; i < 4; ++i) {
    // rows row0+i*16 .. +3 are consecutive -> one float4 load of xsq
    const float4 xr4 = *(const float4*)(xsq + row0 + i * 16);
    const float xr[4] = {xr4.x, xr4.y, xr4.z, xr4.w};
    #pragma unroll
    for (int r = 0; r < 4; ++r) {
      const int rg = row0 + i * 16 + r;
      float* orow = out + (size_t)rg * (size_t)mcols + col0;
      #pragma unroll
      for (int j = 0; j < 4; ++j) {
        float sq = xr[r] + ysqc[j] - 2.0f * acc[i][j][r];
        sq = fmaxf(sq, 0.0f);
        orow[j * 16] = exp2f(ng2 * sq);
      }
    }
  }
}

extern "C" void kernel_launch(void* const* d_in, const int* in_sizes, int n_in,
                              void* d_out, int out_size, void* d_ws, size_t ws_size,
                              hipStream_t stream) {
  const float* x     = (const float*)d_in[0];
  const float* y     = (const float*)d_in[1];
  const float* gamma = (const float*)d_in[2];
  float* out = (float*)d_out;
  const int d = 128;
  const int n = in_sizes[0] / d;   // 8192
  const int m = in_sizes[1] / d;   // 8192

  // workspace: xb (n*128 fp8) | yb (m*128 fp8) | xsq (n f32) | ysq (m f32)
  unsigned char* xb = (unsigned char*)d_ws;
  unsigned char* yb = xb + (size_t)n * d;
  float* xsq = (float*)(yb + (size_t)m * d);
  float* ysq = xsq + n;

  const int waves  = (n + m + 1) / 2;            // 2 rows per wave
  const int blocks = (waves * 64 + 255) / 256;
  rbf_prep<<<blocks, 256, 0, stream>>>(x, y, xb, yb, xsq, ysq, n, m);

  dim3 grid(m / 128, n / 128);
  rbf_gemm<<<grid, 256, 0, stream>>>(xb, yb, xsq, ysq, gamma, out, m);
}